// Round 1
// baseline (502.216 us; speedup 1.0000x reference)
//
#include <hip/hip_runtime.h>
#include <math.h>

#define B 32
#define C 256
#define L 8192
#define H 16

// ---------------------------------------------------------------------------
// Kernel 1: per-(b,c) row mean over L. One 256-thread block per row.
// Each thread loads 8 float4 (32 floats) coalesced, wave shuffle-reduce,
// then 4-wave LDS combine.
// ---------------------------------------------------------------------------
__global__ __launch_bounds__(256) void k_mean(const float* __restrict__ x,
                                              float* __restrict__ y) {
    const int row = blockIdx.x;  // b*C + c
    const float4* xr = (const float4*)(x + (size_t)row * L);
    float s = 0.f;
#pragma unroll
    for (int i = 0; i < 8; ++i) {
        float4 v = xr[threadIdx.x + i * 256];
        s += (v.x + v.y) + (v.z + v.w);
    }
    // reduce across the 64-lane wave
#pragma unroll
    for (int off = 32; off > 0; off >>= 1)
        s += __shfl_down(s, off, 64);
    __shared__ float ws[4];
    const int lane = threadIdx.x & 63;
    const int wave = threadIdx.x >> 6;
    if (lane == 0) ws[wave] = s;
    __syncthreads();
    if (threadIdx.x == 0) {
        float t = (ws[0] + ws[1]) + (ws[2] + ws[3]);
        y[row] = t * (1.0f / (float)L);
    }
}

// ---------------------------------------------------------------------------
// Kernel 2: tiny bottleneck MLP. One block per batch element.
// h[j] = relu(sum_c y[c] * W1[j,c]);  g[c] = sigmoid(sum_j h[j] * W2[c,j])
// ---------------------------------------------------------------------------
__global__ __launch_bounds__(256) void k_mlp(const float* __restrict__ y,
                                             const float* __restrict__ W1,
                                             const float* __restrict__ W2,
                                             float* __restrict__ g) {
    const int b = blockIdx.x;
    __shared__ float ys[C];
    __shared__ float hs[H];
    ys[threadIdx.x] = y[b * C + threadIdx.x];
    __syncthreads();
    if (threadIdx.x < H) {
        float s = 0.f;
        const float* w = W1 + threadIdx.x * C;
#pragma unroll 8
        for (int c = 0; c < C; ++c) s += ys[c] * w[c];
        hs[threadIdx.x] = fmaxf(s, 0.f);
    }
    __syncthreads();
    float s = 0.f;
    const float* w2 = W2 + threadIdx.x * H;
#pragma unroll
    for (int j = 0; j < H; ++j) s += hs[j] * w2[j];
    g[b * C + threadIdx.x] = 1.0f / (1.0f + __expf(-s));
}

// ---------------------------------------------------------------------------
// Kernel 3: out = x * g[row]. Grid-stride float4. L/4 = 2048 vec4 per row,
// so gate index = vec4_idx >> 11.
// ---------------------------------------------------------------------------
__global__ __launch_bounds__(256) void k_scale(const float* __restrict__ x,
                                               const float* __restrict__ g,
                                               float* __restrict__ out) {
    const size_t total = (size_t)B * C * L / 4;
    const size_t stride = (size_t)gridDim.x * blockDim.x;
    const float4* xv = (const float4*)x;
    float4* ov = (float4*)out;
    for (size_t i = (size_t)blockIdx.x * blockDim.x + threadIdx.x; i < total;
         i += stride) {
        const float gg = g[i >> 11];
        float4 v = xv[i];
        v.x *= gg; v.y *= gg; v.z *= gg; v.w *= gg;
        ov[i] = v;
    }
}

extern "C" void kernel_launch(void* const* d_in, const int* in_sizes, int n_in,
                              void* d_out, int out_size, void* d_ws, size_t ws_size,
                              hipStream_t stream) {
    const float* x  = (const float*)d_in[0];   // [B, C, L]
    const float* W1 = (const float*)d_in[1];   // [H, C]
    const float* W2 = (const float*)d_in[2];   // [C, H]
    float* out = (float*)d_out;                // [B, C, L]

    float* y = (float*)d_ws;                   // [B*C] means
    float* g = y + B * C;                      // [B*C] gates

    k_mean<<<B * C, 256, 0, stream>>>(x, y);
    k_mlp<<<B, 256, 0, stream>>>(y, W1, W2, g);
    k_scale<<<4096, 256, 0, stream>>>(x, g, out);
}

// Round 2
// 475.789 us; speedup vs baseline: 1.0555x; 1.0555x over previous
//
#include <hip/hip_runtime.h>
#include <math.h>

#define B 32
#define C 256
#define L 8192
#define H 16

typedef float v4f __attribute__((ext_vector_type(4)));

// ---------------------------------------------------------------------------
// Kernel 1: per-(b,c) row mean over L. One 256-thread block per row.
// Coalesced float4 loads (normal loads -> warm L3 with x for k_scale).
// ---------------------------------------------------------------------------
__global__ __launch_bounds__(256) void k_mean(const float* __restrict__ x,
                                              float* __restrict__ y) {
    const int row = blockIdx.x;  // b*C + c
    const v4f* xr = (const v4f*)(x + (size_t)row * L);
    float s = 0.f;
#pragma unroll
    for (int i = 0; i < 8; ++i) {
        v4f v = xr[threadIdx.x + i * 256];
        s += (v.x + v.y) + (v.z + v.w);
    }
#pragma unroll
    for (int off = 32; off > 0; off >>= 1)
        s += __shfl_down(s, off, 64);
    __shared__ float ws[4];
    const int lane = threadIdx.x & 63;
    const int wave = threadIdx.x >> 6;
    if (lane == 0) ws[wave] = s;
    __syncthreads();
    if (threadIdx.x == 0) {
        float t = (ws[0] + ws[1]) + (ws[2] + ws[3]);
        y[row] = t * (1.0f / (float)L);
    }
}

// ---------------------------------------------------------------------------
// Kernel 2: tiny bottleneck MLP, one block per batch element.
// All 256 threads participate in the first matvec: thread (j = tid&15,
// k = tid>>4) computes a 16-wide partial of h[j]; LDS-reduce; then each
// thread computes its own gate.
// ---------------------------------------------------------------------------
__global__ __launch_bounds__(256) void k_mlp(const float* __restrict__ y,
                                             const float* __restrict__ W1,
                                             const float* __restrict__ W2,
                                             float* __restrict__ g) {
    const int b = blockIdx.x;
    __shared__ float ys[C];
    __shared__ float part[16][H + 1];
    __shared__ float hs[H];
    ys[threadIdx.x] = y[b * C + threadIdx.x];
    __syncthreads();
    {
        const int j = threadIdx.x & 15;   // h unit
        const int k = threadIdx.x >> 4;   // c chunk
        const float* w = W1 + j * C + k * 16;
        const float* yy = ys + k * 16;
        float s = 0.f;
#pragma unroll
        for (int c = 0; c < 16; ++c) s += yy[c] * w[c];
        part[k][j] = s;
    }
    __syncthreads();
    if (threadIdx.x < H) {
        float s = 0.f;
#pragma unroll
        for (int k = 0; k < 16; ++k) s += part[k][threadIdx.x];
        hs[threadIdx.x] = fmaxf(s, 0.f);
    }
    __syncthreads();
    float s = 0.f;
    const float* w2 = W2 + threadIdx.x * H;
#pragma unroll
    for (int j = 0; j < H; ++j) s += hs[j] * w2[j];
    g[b * C + threadIdx.x] = 1.0f / (1.0f + __expf(-s));
}

// ---------------------------------------------------------------------------
// Kernel 3: out[row] = x[row] * g[row]. One block per row; gate is a
// wave-uniform scalar load. Nontemporal stores keep x resident in L3
// (x is exactly 256 MiB = L3 size, warmed by k_mean) so the re-read of x
// is L3-served and this kernel is HBM-write-bound only.
// ---------------------------------------------------------------------------
__global__ __launch_bounds__(256) void k_scale(const float* __restrict__ x,
                                               const float* __restrict__ g,
                                               float* __restrict__ out) {
    const int row = blockIdx.x;
    const float gg = g[row];
    const v4f* xr = (const v4f*)(x + (size_t)row * L);
    v4f* orow = (v4f*)(out + (size_t)row * L);
#pragma unroll
    for (int i = 0; i < 8; ++i) {
        v4f v = xr[threadIdx.x + i * 256];
        v.x *= gg; v.y *= gg; v.z *= gg; v.w *= gg;
        __builtin_nontemporal_store(v, &orow[threadIdx.x + i * 256]);
    }
}

extern "C" void kernel_launch(void* const* d_in, const int* in_sizes, int n_in,
                              void* d_out, int out_size, void* d_ws, size_t ws_size,
                              hipStream_t stream) {
    const float* x  = (const float*)d_in[0];   // [B, C, L]
    const float* W1 = (const float*)d_in[1];   // [H, C]
    const float* W2 = (const float*)d_in[2];   // [C, H]
    float* out = (float*)d_out;                // [B, C, L]

    float* y = (float*)d_ws;                   // [B*C] means
    float* g = y + B * C;                      // [B*C] gates

    k_mean<<<B * C, 256, 0, stream>>>(x, y);
    k_mlp<<<B, 256, 0, stream>>>(y, W1, W2, g);
    k_scale<<<B * C, 256, 0, stream>>>(x, g, out);
}